// Round 1
// baseline (236.603 us; speedup 1.0000x reference)
//
#include <hip/hip_runtime.h>
#include <stdint.h>

#define NB 4
#define NS 2048
#define NHID 768
#define NNH 12
#define NHD 64
#define NBH 48
#define LDK 72   // 64 + 8 bf16 pad: row stride 144B = 9*16B (keeps b128 alignment, kills conflicts)

typedef __attribute__((ext_vector_type(8))) __bf16 bf16x8;
typedef __attribute__((ext_vector_type(4))) float f32x4;

static __device__ __forceinline__ unsigned short f2bf(float f) {
  union { float f; uint32_t u; } v; v.f = f;
  uint32_t r = (v.u + 0x7FFFu + ((v.u >> 16) & 1u)) >> 16;  // RNE
  return (unsigned short)r;
}

// ---------------- kernel 0: fp32 -> bf16 (X and W concat) ----------------
__global__ void cvt_kernel(const float* __restrict__ X,
                           const float* __restrict__ Wq,
                           const float* __restrict__ Wk,
                           const float* __restrict__ Wv,
                           unsigned short* __restrict__ xb,
                           unsigned short* __restrict__ wb) {
  const int NX = NB * NS * NHID;   // 6291456
  const int NW = NHID * NHID;      // 589824
  int i = (blockIdx.x * blockDim.x + threadIdx.x) * 4;
  if (i < NX) {
    const float4 v = *(const float4*)(X + i);
    ushort4 o;
    o.x = f2bf(v.x); o.y = f2bf(v.y); o.z = f2bf(v.z); o.w = f2bf(v.w);
    *(ushort4*)(xb + i) = o;
  } else {
    int j = i - NX;
    const float* W; int jj;
    if (j < NW)          { W = Wq; jj = j; }
    else if (j < 2 * NW) { W = Wk; jj = j - NW; }
    else                 { W = Wv; jj = j - 2 * NW; }
    const float4 v = *(const float4*)(W + jj);
    ushort4 o;
    o.x = f2bf(v.x); o.y = f2bf(v.y); o.z = f2bf(v.z); o.w = f2bf(v.w);
    *(ushort4*)(wb + j) = o;
  }
}

// ---------------- kernel 1: fused QKV projection GEMM ----------------
// C[m,n] = sum_k X[m,k] * W[n,k]  (+bias). 128x128 tile, BK=64, 4 waves.
__global__ void qkv_gemm(const unsigned short* __restrict__ xb,   // [8192][768] bf16
                         const unsigned short* __restrict__ wb,   // [3][768][768] bf16
                         const float* __restrict__ bq,
                         const float* __restrict__ bk,
                         const float* __restrict__ bv,
                         unsigned short* __restrict__ qw,   // [48][2048][64] (pre-scaled 0.125)
                         unsigned short* __restrict__ kw,   // [48][2048][64]
                         unsigned short* __restrict__ vw) { // [48][64][2048] (transposed)
  __shared__ unsigned short As[128 * LDK];
  __shared__ unsigned short Bs[128 * LDK];
  const int tid = threadIdx.x;
  const int lane = tid & 63, wid = tid >> 6;
  const int l15 = lane & 15, l4 = lane >> 4;
  const int wr = wid >> 1, wc = wid & 1;
  const int mblock = blockIdx.x;   // 0..63
  const int ct = blockIdx.y;       // 0..17
  const int which = ct / 6, ctn = ct % 6;
  const int mbase = mblock * 128, nbase = ctn * 128;
  const unsigned short* Wb = wb + (size_t)which * NHID * NHID;

  f32x4 acc[4][4];
  const f32x4 fzero = {0.f, 0.f, 0.f, 0.f};
#pragma unroll
  for (int mi = 0; mi < 4; ++mi)
#pragma unroll
    for (int ni = 0; ni < 4; ++ni) acc[mi][ni] = fzero;

  for (int kt = 0; kt < 12; ++kt) {
    __syncthreads();
#pragma unroll
    for (int i = 0; i < 4; ++i) {
      int idx = i * 256 + tid;            // 0..1023
      int r = idx >> 3, c8 = (idx & 7) * 8;
      uint4 va = *(const uint4*)(xb + (size_t)(mbase + r) * NHID + kt * 64 + c8);
      *(uint4*)(As + r * LDK + c8) = va;
      uint4 vb = *(const uint4*)(Wb + (size_t)(nbase + r) * NHID + kt * 64 + c8);
      *(uint4*)(Bs + r * LDK + c8) = vb;
    }
    __syncthreads();
#pragma unroll
    for (int ks = 0; ks < 2; ++ks) {
      bf16x8 af[4], bf[4];
#pragma unroll
      for (int mi = 0; mi < 4; ++mi)
        af[mi] = *(const bf16x8*)(As + (wr * 64 + mi * 16 + l15) * LDK + ks * 32 + l4 * 8);
#pragma unroll
      for (int ni = 0; ni < 4; ++ni)
        bf[ni] = *(const bf16x8*)(Bs + (wc * 64 + ni * 16 + l15) * LDK + ks * 32 + l4 * 8);
#pragma unroll
      for (int mi = 0; mi < 4; ++mi)
#pragma unroll
        for (int ni = 0; ni < 4; ++ni)
          acc[mi][ni] = __builtin_amdgcn_mfma_f32_16x16x32_bf16(af[mi], bf[ni], acc[mi][ni], 0, 0, 0);
    }
  }

  const float* bias = (which == 0) ? bq : (which == 1) ? bk : bv;
#pragma unroll
  for (int mi = 0; mi < 4; ++mi) {
    int row0 = mbase + wr * 64 + mi * 16 + l4 * 4;
    int b = row0 >> 11, s0 = row0 & 2047;
#pragma unroll
    for (int ni = 0; ni < 4; ++ni) {
      int col = nbase + wc * 64 + ni * 16 + l15;   // 0..767
      float bv_ = bias[col];
      int h = col >> 6, d = col & 63;
      if (which == 2) {
        // V: transposed store [bh][d][s] — 4 consecutive s pack into one 8B store
        ushort4 o;
        o.x = f2bf(acc[mi][ni][0] + bv_);
        o.y = f2bf(acc[mi][ni][1] + bv_);
        o.z = f2bf(acc[mi][ni][2] + bv_);
        o.w = f2bf(acc[mi][ni][3] + bv_);
        *(ushort4*)(vw + ((size_t)(b * NNH + h) * NHD + d) * NS + s0) = o;
      } else {
        unsigned short* dst = (which == 0) ? qw : kw;
        float sc = (which == 0) ? 0.125f : 1.0f;   // fold 1/sqrt(64) into Q (exact)
#pragma unroll
        for (int r = 0; r < 4; ++r) {
          float val = (acc[mi][ni][r] + bv_) * sc;
          dst[((size_t)(b * NNH + h) * NS + (s0 + r)) * NHD + d] = f2bf(val);
        }
      }
    }
  }
}

// ---------------- kernel 2: flash attention ----------------
// grid (16 qblocks, 48 bh), 4 waves; each wave owns 32 q-rows. KVBLK=64.
__global__ void attn_kernel(const unsigned short* __restrict__ qw,
                            const unsigned short* __restrict__ kw,
                            const unsigned short* __restrict__ vw,
                            const float* __restrict__ mask,
                            float* __restrict__ out) {
  __shared__ unsigned short kt_s[64 * LDK];
  __shared__ unsigned short vt_s[64 * LDK];
  __shared__ unsigned short pt_s[4][32 * LDK];

  const int tid = threadIdx.x;
  const int lane = tid & 63, wid = tid >> 6;
  const int l15 = lane & 15, l4 = lane >> 4;
  const int qb = blockIdx.x;   // 0..15
  const int bh = blockIdx.y;   // 0..47
  const int b = bh / NNH, h = bh % NNH;
  const size_t bh_off = (size_t)bh * NS * NHD;

  // hoist Q fragments (rows = qb*128 + wid*32 + mi*16 + l15; k = ks*32 + l4*8)
  bf16x8 qf[2][2];
#pragma unroll
  for (int mi = 0; mi < 2; ++mi)
#pragma unroll
    for (int ks = 0; ks < 2; ++ks)
      qf[mi][ks] = *(const bf16x8*)(qw + bh_off +
          (size_t)(qb * 128 + wid * 32 + mi * 16 + l15) * NHD + ks * 32 + l4 * 8);

  f32x4 oacc[2][4];
  const f32x4 fzero = {0.f, 0.f, 0.f, 0.f};
#pragma unroll
  for (int mi = 0; mi < 2; ++mi)
#pragma unroll
    for (int di = 0; di < 4; ++di) oacc[mi][di] = fzero;
  float mrun[2][4], lrun[2][4];
#pragma unroll
  for (int mi = 0; mi < 2; ++mi)
#pragma unroll
    for (int r = 0; r < 4; ++r) { mrun[mi][r] = -__builtin_inff(); lrun[mi][r] = 0.f; }

  const float* maskb = mask + b * NS;
  const int key_s = tid >> 2, part = tid & 3;

  for (int t = 0; t < 32; ++t) {
    __syncthreads();   // protect LDS from previous iteration's readers
    {
      const uint4* gk = (const uint4*)(kw + bh_off + (size_t)(t * 64 + key_s) * NHD + part * 16);
      uint4 a0 = gk[0], a1 = gk[1];
      const uint4* gv = (const uint4*)(vw + bh_off + (size_t)key_s * NS + t * 64 + part * 16);
      uint4 b0 = gv[0], b1 = gv[1];
      *(uint4*)(kt_s + key_s * LDK + part * 16)     = a0;
      *(uint4*)(kt_s + key_s * LDK + part * 16 + 8) = a1;
      *(uint4*)(vt_s + key_s * LDK + part * 16)     = b0;
      *(uint4*)(vt_s + key_s * LDK + part * 16 + 8) = b1;
    }
    __syncthreads();

    // S = (Q*0.125) K^T  -> 32 rows x 64 keys per wave
    f32x4 sa[2][4];
#pragma unroll
    for (int mi = 0; mi < 2; ++mi)
#pragma unroll
      for (int ni = 0; ni < 4; ++ni) sa[mi][ni] = fzero;
#pragma unroll
    for (int ks = 0; ks < 2; ++ks) {
      bf16x8 kf[4];
#pragma unroll
      for (int ni = 0; ni < 4; ++ni)
        kf[ni] = *(const bf16x8*)(kt_s + (ni * 16 + l15) * LDK + ks * 32 + l4 * 8);
#pragma unroll
      for (int mi = 0; mi < 2; ++mi)
#pragma unroll
        for (int ni = 0; ni < 4; ++ni)
          sa[mi][ni] = __builtin_amdgcn_mfma_f32_16x16x32_bf16(qf[mi][ks], kf[ni], sa[mi][ni], 0, 0, 0);
    }
    float mk[4];
#pragma unroll
    for (int ni = 0; ni < 4; ++ni) mk[ni] = maskb[t * 64 + ni * 16 + l15];

    // online softmax per (mi, reg) row; row spans 4 ni in-lane x 16 lanes
#pragma unroll
    for (int mi = 0; mi < 2; ++mi) {
#pragma unroll
      for (int r = 0; r < 4; ++r) {
        float s0 = sa[mi][0][r] + mk[0];
        float s1 = sa[mi][1][r] + mk[1];
        float s2 = sa[mi][2][r] + mk[2];
        float s3 = sa[mi][3][r] + mk[3];
        float mx = fmaxf(fmaxf(s0, s1), fmaxf(s2, s3));
        mx = fmaxf(mx, __shfl_xor(mx, 1));
        mx = fmaxf(mx, __shfl_xor(mx, 2));
        mx = fmaxf(mx, __shfl_xor(mx, 4));
        mx = fmaxf(mx, __shfl_xor(mx, 8));
        float mnew = fmaxf(mrun[mi][r], mx);
        float alpha = __expf(mrun[mi][r] - mnew);
        mrun[mi][r] = mnew;
        float p0 = __expf(s0 - mnew), p1 = __expf(s1 - mnew);
        float p2 = __expf(s2 - mnew), p3 = __expf(s3 - mnew);
        sa[mi][0][r] = p0; sa[mi][1][r] = p1; sa[mi][2][r] = p2; sa[mi][3][r] = p3;
        float rs = p0 + p1 + p2 + p3;
        rs += __shfl_xor(rs, 1);
        rs += __shfl_xor(rs, 2);
        rs += __shfl_xor(rs, 4);
        rs += __shfl_xor(rs, 8);
        lrun[mi][r] = lrun[mi][r] * alpha + rs;
#pragma unroll
        for (int di = 0; di < 4; ++di) oacc[mi][di][r] *= alpha;
      }
    }

    // P -> bf16 -> per-wave LDS (C-layout scatter), then re-read in A-layout
    unsigned short* pw = pt_s[wid];
#pragma unroll
    for (int mi = 0; mi < 2; ++mi)
#pragma unroll
      for (int ni = 0; ni < 4; ++ni)
#pragma unroll
        for (int r = 0; r < 4; ++r)
          pw[(mi * 16 + l4 * 4 + r) * LDK + ni * 16 + l15] = f2bf(sa[mi][ni][r]);
    __syncthreads();

    // O += P V
#pragma unroll
    for (int ks = 0; ks < 2; ++ks) {
      bf16x8 pa[2], vf[4];
#pragma unroll
      for (int mi = 0; mi < 2; ++mi)
        pa[mi] = *(const bf16x8*)(pw + (mi * 16 + l15) * LDK + ks * 32 + l4 * 8);
#pragma unroll
      for (int di = 0; di < 4; ++di)
        vf[di] = *(const bf16x8*)(vt_s + (di * 16 + l15) * LDK + ks * 32 + l4 * 8);
#pragma unroll
      for (int mi = 0; mi < 2; ++mi)
#pragma unroll
        for (int di = 0; di < 4; ++di)
          oacc[mi][di] = __builtin_amdgcn_mfma_f32_16x16x32_bf16(pa[mi], vf[di], oacc[mi][di], 0, 0, 0);
    }
  }

  // epilogue: normalize and store fp32, merge-heads layout [B,S,HID]
#pragma unroll
  for (int mi = 0; mi < 2; ++mi)
#pragma unroll
    for (int di = 0; di < 4; ++di)
#pragma unroll
      for (int r = 0; r < 4; ++r) {
        int srow = qb * 128 + wid * 32 + mi * 16 + l4 * 4 + r;
        float val = oacc[mi][di][r] / lrun[mi][r];
        out[((size_t)b * NS + srow) * NHID + h * 64 + di * 16 + l15] = val;
      }
}

extern "C" void kernel_launch(void* const* d_in, const int* in_sizes, int n_in,
                              void* d_out, int out_size, void* d_ws, size_t ws_size,
                              hipStream_t stream) {
  const float* X    = (const float*)d_in[0];
  const float* mask = (const float*)d_in[1];
  const float* Wq   = (const float*)d_in[2];
  const float* bq   = (const float*)d_in[3];
  const float* Wk   = (const float*)d_in[4];
  const float* bk   = (const float*)d_in[5];
  const float* Wv   = (const float*)d_in[6];
  const float* bv   = (const float*)d_in[7];
  float* out = (float*)d_out;

  // d_out doubles as scratch for bf16 X and W (16.1 MB < 25.2 MB); fully
  // overwritten by attn_kernel at the end. qkv bf16 tensors live in d_ws (37.7 MB).
  unsigned short* xb = (unsigned short*)d_out;
  unsigned short* wb = xb + (size_t)NB * NS * NHID;
  unsigned short* qw = (unsigned short*)d_ws;
  unsigned short* kw = qw + (size_t)NBH * NS * NHD;
  unsigned short* vw = kw + (size_t)NBH * NS * NHD;

  cvt_kernel<<<7872, 256, 0, stream>>>(X, Wq, Wk, Wv, xb, wb);
  qkv_gemm<<<dim3(64, 18), 256, 0, stream>>>(xb, wb, bq, bk, bv, qw, kw, vw);
  attn_kernel<<<dim3(16, 48), 256, 0, stream>>>(qw, kw, vw, mask, out);
}

// Round 4
// 140.431 us; speedup vs baseline: 1.6848x; 1.6848x over previous
//
#include <hip/hip_runtime.h>
#include <stdint.h>

#define NB 4
#define NS 2048
#define NHID 768
#define NNH 12
#define NHD 64
#define NBH 48
#define LDK 72   // GEMM LDS pad

typedef __attribute__((ext_vector_type(8))) __bf16 bf16x8;
typedef __attribute__((ext_vector_type(4))) float f32x4;
typedef __attribute__((ext_vector_type(16))) float f32x16;

static __device__ __forceinline__ unsigned short f2bf(float f) {
  union { float f; uint32_t u; } v; v.f = f;
  uint32_t r = (v.u + 0x7FFFu + ((v.u >> 16) & 1u)) >> 16;  // RNE
  return (unsigned short)r;
}

static __device__ __forceinline__ unsigned int cvtpk(float lo, float hi) {
  unsigned int r;
  asm("v_cvt_pk_bf16_f32 %0, %1, %2" : "=v"(r) : "v"(lo), "v"(hi));
  return r;
}

#define GLDS(src, dst) __builtin_amdgcn_global_load_lds( \
    (const __attribute__((address_space(1))) void*)(src), \
    (__attribute__((address_space(3))) void*)(dst), 16, 0, 0)

// ---------------- kernel 0: fp32 -> bf16 (X and W concat) ----------------
__global__ void cvt_kernel(const float* __restrict__ X,
                           const float* __restrict__ Wq,
                           const float* __restrict__ Wk,
                           const float* __restrict__ Wv,
                           unsigned short* __restrict__ xb,
                           unsigned short* __restrict__ wb) {
  const int NX = NB * NS * NHID;   // 6291456
  const int NW = NHID * NHID;      // 589824
  int i = (blockIdx.x * blockDim.x + threadIdx.x) * 4;
  if (i < NX) {
    const float4 v = *(const float4*)(X + i);
    ushort4 o;
    o.x = f2bf(v.x); o.y = f2bf(v.y); o.z = f2bf(v.z); o.w = f2bf(v.w);
    *(ushort4*)(xb + i) = o;
  } else {
    int j = i - NX;
    const float* W; int jj;
    if (j < NW)          { W = Wq; jj = j; }
    else if (j < 2 * NW) { W = Wk; jj = j - NW; }
    else                 { W = Wv; jj = j - 2 * NW; }
    const float4 v = *(const float4*)(W + jj);
    ushort4 o;
    o.x = f2bf(v.x); o.y = f2bf(v.y); o.z = f2bf(v.z); o.w = f2bf(v.w);
    *(ushort4*)(wb + j) = o;
  }
}

// ---------------- kernel 1: fused QKV projection GEMM ----------------
__global__ void qkv_gemm(const unsigned short* __restrict__ xb,   // [8192][768] bf16
                         const unsigned short* __restrict__ wb,   // [3][768][768] bf16
                         const float* __restrict__ bq,
                         const float* __restrict__ bk,
                         const float* __restrict__ bv,
                         unsigned short* __restrict__ qw,   // [48][2048][64] (pre-scaled 0.125)
                         unsigned short* __restrict__ kw,   // [48][2048][64]
                         unsigned short* __restrict__ vw) { // [48][64][2048] (transposed)
  __shared__ unsigned short As[128 * LDK];
  __shared__ unsigned short Bs[128 * LDK];
  const int tid = threadIdx.x;
  const int lane = tid & 63, wid = tid >> 6;
  const int l15 = lane & 15, l4 = lane >> 4;
  const int wr = wid >> 1, wc = wid & 1;
  const int mblock = blockIdx.x;   // 0..63
  const int ct = blockIdx.y;       // 0..17
  const int which = ct / 6, ctn = ct % 6;
  const int mbase = mblock * 128, nbase = ctn * 128;
  const unsigned short* Wb = wb + (size_t)which * NHID * NHID;

  f32x4 acc[4][4];
  const f32x4 fzero = {0.f, 0.f, 0.f, 0.f};
#pragma unroll
  for (int mi = 0; mi < 4; ++mi)
#pragma unroll
    for (int ni = 0; ni < 4; ++ni) acc[mi][ni] = fzero;

  for (int kt = 0; kt < 12; ++kt) {
    __syncthreads();
#pragma unroll
    for (int i = 0; i < 4; ++i) {
      int idx = i * 256 + tid;            // 0..1023
      int r = idx >> 3, c8 = (idx & 7) * 8;
      uint4 va = *(const uint4*)(xb + (size_t)(mbase + r) * NHID + kt * 64 + c8);
      *(uint4*)(As + r * LDK + c8) = va;
      uint4 vb = *(const uint4*)(Wb + (size_t)(nbase + r) * NHID + kt * 64 + c8);
      *(uint4*)(Bs + r * LDK + c8) = vb;
    }
    __syncthreads();
#pragma unroll
    for (int ks = 0; ks < 2; ++ks) {
      bf16x8 af[4], bf[4];
#pragma unroll
      for (int mi = 0; mi < 4; ++mi)
        af[mi] = *(const bf16x8*)(As + (wr * 64 + mi * 16 + l15) * LDK + ks * 32 + l4 * 8);
#pragma unroll
      for (int ni = 0; ni < 4; ++ni)
        bf[ni] = *(const bf16x8*)(Bs + (wc * 64 + ni * 16 + l15) * LDK + ks * 32 + l4 * 8);
#pragma unroll
      for (int mi = 0; mi < 4; ++mi)
#pragma unroll
        for (int ni = 0; ni < 4; ++ni)
          acc[mi][ni] = __builtin_amdgcn_mfma_f32_16x16x32_bf16(af[mi], bf[ni], acc[mi][ni], 0, 0, 0);
    }
  }

  const float* bias = (which == 0) ? bq : (which == 1) ? bk : bv;
#pragma unroll
  for (int mi = 0; mi < 4; ++mi) {
    int row0 = mbase + wr * 64 + mi * 16 + l4 * 4;
    int b = row0 >> 11, s0 = row0 & 2047;
#pragma unroll
    for (int ni = 0; ni < 4; ++ni) {
      int col = nbase + wc * 64 + ni * 16 + l15;   // 0..767
      float bv_ = bias[col];
      int h = col >> 6, d = col & 63;
      if (which == 2) {
        ushort4 o;
        o.x = f2bf(acc[mi][ni][0] + bv_);
        o.y = f2bf(acc[mi][ni][1] + bv_);
        o.z = f2bf(acc[mi][ni][2] + bv_);
        o.w = f2bf(acc[mi][ni][3] + bv_);
        *(ushort4*)(vw + ((size_t)(b * NNH + h) * NHD + d) * NS + s0) = o;
      } else {
        unsigned short* dst = (which == 0) ? qw : kw;
        float sc = (which == 0) ? 0.125f : 1.0f;   // fold 1/sqrt(64) into Q (exact)
#pragma unroll
        for (int r = 0; r < 4; ++r) {
          float val = (acc[mi][ni][r] + bv_) * sc;
          dst[((size_t)(b * NNH + h) * NS + (s0 + r)) * NHD + d] = f2bf(val);
        }
      }
    }
  }
}

// ---------------- kernel 2: flash attention, 32x32 swapped-QK^T ----------------
// grid (16 qblocks, 48 bh), 4 waves; wave owns 32 q rows.
// Softmax domain: lane (l31,hi) owns stats for q = l31 (S^T col).
// O domain (C-layout): lane holds d-col = l31, q-rows = (reg&3)+8*(reg>>2)+4*hi.
// Per-q scalars (alpha, 1/l) must be routed softmax-domain -> O-domain via __shfl.
__global__ __launch_bounds__(256, 3)
void attn_kernel(const unsigned short* __restrict__ qw,
                 const unsigned short* __restrict__ kw,
                 const unsigned short* __restrict__ vw,
                 const float* __restrict__ mask,
                 float* __restrict__ out) {
  __shared__ unsigned char lds[4][8192];  // [0..1]=K bufs, [2..3]=V bufs

  const int tid = threadIdx.x;
  const int lane = tid & 63, wid = tid >> 6;
  const int l31 = lane & 31, hi = lane >> 5;
  const int qb = blockIdx.x;   // 0..15
  const int bh = blockIdx.y;   // 0..47
  const int b = bh / NNH, h = bh % NNH;
  const size_t bh_off = (size_t)bh * NS * NHD;
  const int qbase = qb * 128 + wid * 32;

  // hoist Q B-fragments: Q[q = qbase+l31][d = dk*16 + hi*8 + j]
  bf16x8 qf[4];
#pragma unroll
  for (int dk = 0; dk < 4; ++dk)
    qf[dk] = *(const bf16x8*)(qw + bh_off + (size_t)(qbase + l31) * NHD + dk * 16 + hi * 8);

  // staging: per-lane pre-swizzled global offsets (LDS dest is linear)
  const int swz16 = ((lane & 7) * 16) ^ (((lane >> 3) & 7) << 4);
  const unsigned char* kgp = (const unsigned char*)(kw + bh_off);
  const unsigned char* vgp = (const unsigned char*)(vw + bh_off);
  const int kst = (lane >> 3) * 128 + swz16;                 // K tile is contiguous 8KB
  const size_t vst = (size_t)(lane >> 3) * (NS * 2) + swz16; // V^T rows stride 4096B

  // ds_read col offsets (swizzled); row&7 == l31&7 for all our reads
  const int swzr = (l31 & 7) << 4;
  int colA[4];
#pragma unroll
  for (int i = 0; i < 4; ++i) colA[i] = (i * 32 + hi * 16) ^ swzr;

  const float* maskp = mask + b * NS;

  f32x16 oacc[2];
#pragma unroll
  for (int db = 0; db < 2; ++db)
#pragma unroll
    for (int e = 0; e < 16; ++e) oacc[db][e] = 0.f;
  float mrun = -__builtin_inff(), lrun = 0.f;

  const int g0 = wid * 2, g1 = g0 + 1;

#define STAGE(t_, bufi_) do { \
    GLDS(kgp + (size_t)(t_) * 8192 + g0 * 1024 + kst, &lds[(bufi_)][g0 * 1024]); \
    GLDS(kgp + (size_t)(t_) * 8192 + g1 * 1024 + kst, &lds[(bufi_)][g1 * 1024]); \
    GLDS(vgp + (size_t)g0 * 8 * (NS * 2) + (size_t)(t_) * 128 + vst, &lds[2 + (bufi_)][g0 * 1024]); \
    GLDS(vgp + (size_t)g1 * 8 * (NS * 2) + (size_t)(t_) * 128 + vst, &lds[2 + (bufi_)][g1 * 1024]); \
  } while (0)

  int bufi = 0;
  STAGE(0, 0);
  __syncthreads();

  for (int t = 0; t < 32; ++t) {
    if (t + 1 < 32) STAGE(t + 1, bufi ^ 1);

    // S^T accumulators, C-init = additive mask (broadcast over q)
    f32x16 acc2[2];
#pragma unroll
    for (int kb = 0; kb < 2; ++kb)
#pragma unroll
      for (int c = 0; c < 4; ++c) {
        float4 mv = *(const float4*)(maskp + t * 64 + kb * 32 + c * 8 + hi * 4);
        acc2[kb][c * 4 + 0] = mv.x;
        acc2[kb][c * 4 + 1] = mv.y;
        acc2[kb][c * 4 + 2] = mv.z;
        acc2[kb][c * 4 + 3] = mv.w;
      }

    // QK^T (swapped): acc2[kb][reg] = S[q=l31][key = kb*32 + (reg&3)+8*(reg>>2)+4*hi]
    const unsigned char* klds = lds[bufi];
    __builtin_amdgcn_s_setprio(1);
#pragma unroll
    for (int kb = 0; kb < 2; ++kb)
#pragma unroll
      for (int dk = 0; dk < 4; ++dk) {
        bf16x8 kf = *(const bf16x8*)(klds + (kb * 32 + l31) * 128 + colA[dk]);
        acc2[kb] = __builtin_amdgcn_mfma_f32_32x32x16_bf16(kf, qf[dk], acc2[kb], 0, 0, 0);
      }
    __builtin_amdgcn_s_setprio(0);

    // in-register online softmax (partner lane l^32 holds the other 32 keys of same q)
    float pmax = acc2[0][0];
#pragma unroll
    for (int e = 1; e < 16; ++e) pmax = fmaxf(pmax, acc2[0][e]);
#pragma unroll
    for (int e = 0; e < 16; ++e) pmax = fmaxf(pmax, acc2[1][e]);
    pmax = fmaxf(pmax, __shfl_xor(pmax, 32));

    if (!__all(pmax - mrun <= 8.0f)) {   // T13 defer-max; wave-uniform branch
      float mnew = fmaxf(mrun, pmax);
      float alpha = __expf(mrun - mnew);   // alpha for q = l31 (softmax domain)
      lrun *= alpha;
      // route alpha to O-domain rows: reg r holds q_local = (r&3)+8*(r>>2)+4*hi
#pragma unroll
      for (int r = 0; r < 16; ++r) {
        float a_r = __shfl(alpha, (r & 3) + 8 * (r >> 2) + 4 * hi);
        oacc[0][r] *= a_r;
        oacc[1][r] *= a_r;
      }
      mrun = mnew;
    }

    float rsum = 0.f;
#pragma unroll
    for (int kb = 0; kb < 2; ++kb)
#pragma unroll
      for (int e = 0; e < 16; ++e) {
        float p = __expf(acc2[kb][e] - mrun);
        acc2[kb][e] = p;
        rsum += p;
      }
    rsum += __shfl_xor(rsum, 32);
    lrun += rsum;

    // P -> bf16 packed words. w[kb*4+c][wj] = keys {kb*32+c*8+4*hi+2*wj, +1}
    unsigned int w[8][2];
#pragma unroll
    for (int c = 0; c < 8; ++c)
#pragma unroll
      for (int wj = 0; wj < 2; ++wj)
        w[c][wj] = cvtpk(acc2[c >> 2][(c & 3) * 4 + 2 * wj],
                         acc2[c >> 2][(c & 3) * 4 + 2 * wj + 1]);

    // assemble PV A-fragments: af[ks][j] = P[q=l31][key = ks*16 + hi*8 + j]
    bf16x8 af[4];
#pragma unroll
    for (int ks = 0; ks < 4; ++ks) {
      unsigned int s0 = hi ? w[2 * ks][0] : w[2 * ks + 1][0];
      unsigned int s1 = hi ? w[2 * ks][1] : w[2 * ks + 1][1];
      unsigned int r0 = __shfl_xor(s0, 32);
      unsigned int r1 = __shfl_xor(s1, 32);
      union { unsigned int u[4]; bf16x8 v; } afu;
      afu.u[0] = hi ? r0 : w[2 * ks][0];
      afu.u[1] = hi ? r1 : w[2 * ks][1];
      afu.u[2] = hi ? w[2 * ks + 1][0] : r0;
      afu.u[3] = hi ? w[2 * ks + 1][1] : r1;
      af[ks] = afu.v;
    }

    // PV: oacc[db][q][d] += P[q][key] * V[key][d]
    const unsigned char* vlds = lds[2 + bufi];
    __builtin_amdgcn_s_setprio(1);
#pragma unroll
    for (int db = 0; db < 2; ++db)
#pragma unroll
      for (int ks = 0; ks < 4; ++ks) {
        bf16x8 vf = *(const bf16x8*)(vlds + (db * 32 + l31) * 128 + colA[ks]);
        oacc[db] = __builtin_amdgcn_mfma_f32_32x32x16_bf16(af[ks], vf, oacc[db], 0, 0, 0);
      }
    __builtin_amdgcn_s_setprio(0);

    __syncthreads();   // tile t+1 staged (vmcnt drained) + all waves done with buf
    bufi ^= 1;
  }

  // epilogue: route 1/l to O-domain rows, store fp32 merge-heads layout
  float invl = 1.0f / lrun;   // for q = l31 (softmax domain)
#pragma unroll
  for (int reg = 0; reg < 16; ++reg) {
    int q_local = (reg & 3) + 8 * (reg >> 2) + 4 * hi;
    float inv_r = __shfl(invl, q_local);
    int q = qbase + q_local;
    out[((size_t)b * NS + q) * NHID + h * 64 + l31]      = oacc[0][reg] * inv_r;
    out[((size_t)b * NS + q) * NHID + h * 64 + 32 + l31] = oacc[1][reg] * inv_r;
  }
#undef STAGE
}

extern "C" void kernel_launch(void* const* d_in, const int* in_sizes, int n_in,
                              void* d_out, int out_size, void* d_ws, size_t ws_size,
                              hipStream_t stream) {
  const float* X    = (const float*)d_in[0];
  const float* mask = (const float*)d_in[1];
  const float* Wq   = (const float*)d_in[2];
  const float* bq   = (const float*)d_in[3];
  const float* Wk   = (const float*)d_in[4];
  const float* bk   = (const float*)d_in[5];
  const float* Wv   = (const float*)d_in[6];
  const float* bv   = (const float*)d_in[7];
  float* out = (float*)d_out;

  unsigned short* xb = (unsigned short*)d_out;            // scratch, overwritten by attn out
  unsigned short* wb = xb + (size_t)NB * NS * NHID;
  unsigned short* qw = (unsigned short*)d_ws;
  unsigned short* kw = qw + (size_t)NBH * NS * NHD;
  unsigned short* vw = kw + (size_t)NBH * NS * NHD;

  cvt_kernel<<<7872, 256, 0, stream>>>(X, Wq, Wk, Wv, xb, wb);
  qkv_gemm<<<dim3(64, 18), 256, 0, stream>>>(xb, wb, bq, bk, bv, qw, kw, vw);
  attn_kernel<<<dim3(16, 48), 256, 0, stream>>>(qw, kw, vw, mask, out);
}

// Round 5
// 137.615 us; speedup vs baseline: 1.7193x; 1.0205x over previous
//
#include <hip/hip_runtime.h>
#include <stdint.h>

#define NB 4
#define NS 2048
#define NHID 768
#define NNH 12
#define NHD 64
#define NBH 48

typedef __attribute__((ext_vector_type(8))) __bf16 bf16x8;
typedef __attribute__((ext_vector_type(4))) float f32x4;
typedef __attribute__((ext_vector_type(16))) float f32x16;

static __device__ __forceinline__ unsigned short f2bf(float f) {
  union { float f; uint32_t u; } v; v.f = f;
  uint32_t r = (v.u + 0x7FFFu + ((v.u >> 16) & 1u)) >> 16;  // RNE
  return (unsigned short)r;
}

static __device__ __forceinline__ unsigned int cvtpk(float lo, float hi) {
  unsigned int r;
  asm("v_cvt_pk_bf16_f32 %0, %1, %2" : "=v"(r) : "v"(lo), "v"(hi));
  return r;
}

#define GLDS(src, dst) __builtin_amdgcn_global_load_lds( \
    (const __attribute__((address_space(1))) void*)(src), \
    (__attribute__((address_space(3))) void*)(dst), 16, 0, 0)

// ---------------- kernel 0: fp32 -> bf16 (X and W concat) ----------------
__global__ void cvt_kernel(const float* __restrict__ X,
                           const float* __restrict__ Wq,
                           const float* __restrict__ Wk,
                           const float* __restrict__ Wv,
                           unsigned short* __restrict__ xb,
                           unsigned short* __restrict__ wb) {
  const int NX = NB * NS * NHID;   // 6291456
  const int NW = NHID * NHID;      // 589824
  int i = (blockIdx.x * blockDim.x + threadIdx.x) * 4;
  if (i < NX) {
    const float4 v = *(const float4*)(X + i);
    ushort4 o;
    o.x = f2bf(v.x); o.y = f2bf(v.y); o.z = f2bf(v.z); o.w = f2bf(v.w);
    *(ushort4*)(xb + i) = o;
  } else {
    int j = i - NX;
    const float* W; int jj;
    if (j < NW)          { W = Wq; jj = j; }
    else if (j < 2 * NW) { W = Wk; jj = j - NW; }
    else                 { W = Wv; jj = j - 2 * NW; }
    const float4 v = *(const float4*)(W + jj);
    ushort4 o;
    o.x = f2bf(v.x); o.y = f2bf(v.y); o.z = f2bf(v.z); o.w = f2bf(v.w);
    *(ushort4*)(wb + j) = o;
  }
}

// ---------------- kernel 1: fused QKV projection GEMM ----------------
// 128x128 tile, BK=64, 4 waves. global_load_lds(16B) staging into linear
// XOR-swizzled LDS: LDS[r][c] = G[r][c ^ ((r&7)<<4)] (byte units) — same
// involution as the attn kernel's staging (proven round 4).
__global__ void qkv_gemm(const unsigned short* __restrict__ xb,   // [8192][768] bf16
                         const unsigned short* __restrict__ wb,   // [3][768][768] bf16
                         const float* __restrict__ bq,
                         const float* __restrict__ bk,
                         const float* __restrict__ bv,
                         unsigned short* __restrict__ qw,   // [48][2048][64] (pre-scaled 0.125)
                         unsigned short* __restrict__ kw,   // [48][2048][64]
                         unsigned short* __restrict__ vw) { // [48][64][2048] (transposed)
  __shared__ unsigned char As[128 * 128];   // [row][128B K-slab], swizzled
  __shared__ unsigned char Bs[128 * 128];
  const int tid = threadIdx.x;
  const int lane = tid & 63, wid = tid >> 6;
  const int l15 = lane & 15, l4 = lane >> 4;
  const int wr = wid >> 1, wc = wid & 1;
  const int mblock = blockIdx.x;   // 0..63
  const int ct = blockIdx.y;       // 0..17
  const int which = ct / 6, ctn = ct % 6;
  const int mbase = mblock * 128, nbase = ctn * 128;
  const unsigned short* Wb = wb + (size_t)which * NHID * NHID;

  // staging addressing (per lane): row-in-8 = lane>>3, swizzled source col
  const int srow = lane >> 3;                               // 0..7
  const int swz16 = ((lane & 7) * 16) ^ (srow << 4);        // < 128
  const unsigned char* agp = (const unsigned char*)xb + (size_t)mbase * (NHID * 2);
  const unsigned char* bgp = (const unsigned char*)Wb + (size_t)nbase * (NHID * 2);

  f32x4 acc[4][4];
  const f32x4 fzero = {0.f, 0.f, 0.f, 0.f};
#pragma unroll
  for (int mi = 0; mi < 4; ++mi)
#pragma unroll
    for (int ni = 0; ni < 4; ++ni) acc[mi][ni] = fzero;

  const int swzr = (l15 & 7) << 4;   // read-side XOR (row&7 == l15&7)

  for (int kt = 0; kt < 12; ++kt) {
    __syncthreads();
#pragma unroll
    for (int g = 0; g < 4; ++g) {
      int row = wid * 32 + g * 8 + srow;
      GLDS(agp + (size_t)row * (NHID * 2) + kt * 128 + swz16,
           As + (wid * 32 + g * 8) * 128);
      GLDS(bgp + (size_t)row * (NHID * 2) + kt * 128 + swz16,
           Bs + (wid * 32 + g * 8) * 128);
    }
    __syncthreads();   // vmcnt drained by barrier
#pragma unroll
    for (int ks = 0; ks < 2; ++ks) {
      bf16x8 af[4], bf[4];
#pragma unroll
      for (int mi = 0; mi < 4; ++mi)
        af[mi] = *(const bf16x8*)(As + (wr * 64 + mi * 16 + l15) * 128 +
                                  ((ks * 64 + l4 * 16) ^ swzr));
#pragma unroll
      for (int ni = 0; ni < 4; ++ni)
        bf[ni] = *(const bf16x8*)(Bs + (wc * 64 + ni * 16 + l15) * 128 +
                                  ((ks * 64 + l4 * 16) ^ swzr));
#pragma unroll
      for (int mi = 0; mi < 4; ++mi)
#pragma unroll
        for (int ni = 0; ni < 4; ++ni)
          acc[mi][ni] = __builtin_amdgcn_mfma_f32_16x16x32_bf16(af[mi], bf[ni], acc[mi][ni], 0, 0, 0);
    }
  }

  const float* bias = (which == 0) ? bq : (which == 1) ? bk : bv;
#pragma unroll
  for (int mi = 0; mi < 4; ++mi) {
    int row0 = mbase + wr * 64 + mi * 16 + l4 * 4;
    int b = row0 >> 11, s0 = row0 & 2047;
#pragma unroll
    for (int ni = 0; ni < 4; ++ni) {
      int col = nbase + wc * 64 + ni * 16 + l15;   // 0..767
      float bv_ = bias[col];
      int h = col >> 6, d = col & 63;
      if (which == 2) {
        ushort4 o;
        o.x = f2bf(acc[mi][ni][0] + bv_);
        o.y = f2bf(acc[mi][ni][1] + bv_);
        o.z = f2bf(acc[mi][ni][2] + bv_);
        o.w = f2bf(acc[mi][ni][3] + bv_);
        *(ushort4*)(vw + ((size_t)(b * NNH + h) * NHD + d) * NS + s0) = o;
      } else {
        unsigned short* dst = (which == 0) ? qw : kw;
        float sc = (which == 0) ? 0.125f : 1.0f;   // fold 1/sqrt(64) into Q (exact)
#pragma unroll
        for (int r = 0; r < 4; ++r) {
          float val = (acc[mi][ni][r] + bv_) * sc;
          dst[((size_t)(b * NNH + h) * NS + (s0 + r)) * NHD + d] = f2bf(val);
        }
      }
    }
  }
}

// ---------------- kernel 2: flash attention, 32x32 swapped-QK^T ----------------
// 1D grid 768, XCD-aware remap: blocks with (id%8)==x cover bh in [6x,6x+6)
// and all 16 qb -> K/V (3 MB) resident in that XCD's 4 MB L2.
__global__ __launch_bounds__(256, 3)
void attn_kernel(const unsigned short* __restrict__ qw,
                 const unsigned short* __restrict__ kw,
                 const unsigned short* __restrict__ vw,
                 const float* __restrict__ mask,
                 float* __restrict__ out) {
  __shared__ unsigned char lds[4][8192];  // [0..1]=K bufs, [2..3]=V bufs

  const int tid = threadIdx.x;
  const int lane = tid & 63, wid = tid >> 6;
  const int l31 = lane & 31, hi = lane >> 5;
  const int r_ = blockIdx.x;           // 0..767
  const int j_ = r_ >> 3, xcd = r_ & 7;
  const int bh = xcd * 6 + (j_ % 6);   // bh-major per XCD
  const int qb = j_ / 6;               // 0..15
  const int b = bh / NNH, h = bh % NNH;
  const size_t bh_off = (size_t)bh * NS * NHD;
  const int qbase = qb * 128 + wid * 32;

  // hoist Q B-fragments: Q[q = qbase+l31][d = dk*16 + hi*8 + j]
  bf16x8 qf[4];
#pragma unroll
  for (int dk = 0; dk < 4; ++dk)
    qf[dk] = *(const bf16x8*)(qw + bh_off + (size_t)(qbase + l31) * NHD + dk * 16 + hi * 8);

  // staging: per-lane pre-swizzled global offsets (LDS dest is linear)
  const int swz16 = ((lane & 7) * 16) ^ (((lane >> 3) & 7) << 4);
  const unsigned char* kgp = (const unsigned char*)(kw + bh_off);
  const unsigned char* vgp = (const unsigned char*)(vw + bh_off);
  const int kst = (lane >> 3) * 128 + swz16;                 // K tile is contiguous 8KB
  const size_t vst = (size_t)(lane >> 3) * (NS * 2) + swz16; // V^T rows stride 4096B

  // ds_read col offsets (swizzled); row&7 == l31&7 for all our reads
  const int swzr = (l31 & 7) << 4;
  int colA[4];
#pragma unroll
  for (int i = 0; i < 4; ++i) colA[i] = (i * 32 + hi * 16) ^ swzr;

  const float* maskp = mask + b * NS;

  f32x16 oacc[2];
#pragma unroll
  for (int db = 0; db < 2; ++db)
#pragma unroll
    for (int e = 0; e < 16; ++e) oacc[db][e] = 0.f;
  float mrun = -__builtin_inff(), lrun = 0.f;

  const int g0 = wid * 2, g1 = g0 + 1;

#define STAGE(t_, bufi_) do { \
    GLDS(kgp + (size_t)(t_) * 8192 + g0 * 1024 + kst, &lds[(bufi_)][g0 * 1024]); \
    GLDS(kgp + (size_t)(t_) * 8192 + g1 * 1024 + kst, &lds[(bufi_)][g1 * 1024]); \
    GLDS(vgp + (size_t)g0 * 8 * (NS * 2) + (size_t)(t_) * 128 + vst, &lds[2 + (bufi_)][g0 * 1024]); \
    GLDS(vgp + (size_t)g1 * 8 * (NS * 2) + (size_t)(t_) * 128 + vst, &lds[2 + (bufi_)][g1 * 1024]); \
  } while (0)

  int bufi = 0;
  STAGE(0, 0);
  __syncthreads();

  for (int t = 0; t < 32; ++t) {
    if (t + 1 < 32) STAGE(t + 1, bufi ^ 1);

    // S^T accumulators, C-init = additive mask (broadcast over q)
    f32x16 acc2[2];
#pragma unroll
    for (int kb = 0; kb < 2; ++kb)
#pragma unroll
      for (int c = 0; c < 4; ++c) {
        float4 mv = *(const float4*)(maskp + t * 64 + kb * 32 + c * 8 + hi * 4);
        acc2[kb][c * 4 + 0] = mv.x;
        acc2[kb][c * 4 + 1] = mv.y;
        acc2[kb][c * 4 + 2] = mv.z;
        acc2[kb][c * 4 + 3] = mv.w;
      }

    // QK^T (swapped): acc2[kb][reg] = S[q=l31][key = kb*32 + (reg&3)+8*(reg>>2)+4*hi]
    const unsigned char* klds = lds[bufi];
    __builtin_amdgcn_s_setprio(1);
#pragma unroll
    for (int kb = 0; kb < 2; ++kb)
#pragma unroll
      for (int dk = 0; dk < 4; ++dk) {
        bf16x8 kf = *(const bf16x8*)(klds + (kb * 32 + l31) * 128 + colA[dk]);
        acc2[kb] = __builtin_amdgcn_mfma_f32_32x32x16_bf16(kf, qf[dk], acc2[kb], 0, 0, 0);
      }
    __builtin_amdgcn_s_setprio(0);

    // in-register online softmax; balanced trees (depth 5) for the serial chains
    float mx8[8];
#pragma unroll
    for (int e = 0; e < 8; ++e)
      mx8[e] = fmaxf(fmaxf(acc2[0][e], acc2[0][e + 8]),
                     fmaxf(acc2[1][e], acc2[1][e + 8]));
    float pmax = fmaxf(fmaxf(fmaxf(mx8[0], mx8[1]), fmaxf(mx8[2], mx8[3])),
                       fmaxf(fmaxf(mx8[4], mx8[5]), fmaxf(mx8[6], mx8[7])));
    pmax = fmaxf(pmax, __shfl_xor(pmax, 32));

    if (!__all(pmax - mrun <= 8.0f)) {   // T13 defer-max; wave-uniform branch
      float mnew = fmaxf(mrun, pmax);
      float alpha = __expf(mrun - mnew);   // alpha for q = l31 (softmax domain)
      lrun *= alpha;
      // route alpha to O-domain rows: reg r holds q_local = (r&3)+8*(r>>2)+4*hi
#pragma unroll
      for (int r = 0; r < 16; ++r) {
        float a_r = __shfl(alpha, (r & 3) + 8 * (r >> 2) + 4 * hi);
        oacc[0][r] *= a_r;
        oacc[1][r] *= a_r;
      }
      mrun = mnew;
    }

#pragma unroll
    for (int kb = 0; kb < 2; ++kb)
#pragma unroll
      for (int e = 0; e < 16; ++e)
        acc2[kb][e] = __expf(acc2[kb][e] - mrun);
    float s8[8];
#pragma unroll
    for (int e = 0; e < 8; ++e)
      s8[e] = (acc2[0][e] + acc2[0][e + 8]) + (acc2[1][e] + acc2[1][e + 8]);
    float rsum = ((s8[0] + s8[1]) + (s8[2] + s8[3])) +
                 ((s8[4] + s8[5]) + (s8[6] + s8[7]));
    rsum += __shfl_xor(rsum, 32);
    lrun += rsum;

    // P -> bf16 packed words. w[kb*4+c][wj] = keys {kb*32+c*8+4*hi+2*wj, +1}
    unsigned int w[8][2];
#pragma unroll
    for (int c = 0; c < 8; ++c)
#pragma unroll
      for (int wj = 0; wj < 2; ++wj)
        w[c][wj] = cvtpk(acc2[c >> 2][(c & 3) * 4 + 2 * wj],
                         acc2[c >> 2][(c & 3) * 4 + 2 * wj + 1]);

    // assemble PV A-fragments: af[ks][j] = P[q=l31][key = ks*16 + hi*8 + j]
    bf16x8 af[4];
#pragma unroll
    for (int ks = 0; ks < 4; ++ks) {
      unsigned int s0 = hi ? w[2 * ks][0] : w[2 * ks + 1][0];
      unsigned int s1 = hi ? w[2 * ks][1] : w[2 * ks + 1][1];
      unsigned int r0 = __shfl_xor(s0, 32);
      unsigned int r1 = __shfl_xor(s1, 32);
      union { unsigned int u[4]; bf16x8 v; } afu;
      afu.u[0] = hi ? r0 : w[2 * ks][0];
      afu.u[1] = hi ? r1 : w[2 * ks][1];
      afu.u[2] = hi ? w[2 * ks + 1][0] : r0;
      afu.u[3] = hi ? w[2 * ks + 1][1] : r1;
      af[ks] = afu.v;
    }

    // PV: oacc[db][q][d] += P[q][key] * V[key][d]
    const unsigned char* vlds = lds[2 + bufi];
    __builtin_amdgcn_s_setprio(1);
#pragma unroll
    for (int db = 0; db < 2; ++db)
#pragma unroll
      for (int ks = 0; ks < 4; ++ks) {
        bf16x8 vf = *(const bf16x8*)(vlds + (db * 32 + l31) * 128 + colA[ks]);
        oacc[db] = __builtin_amdgcn_mfma_f32_32x32x16_bf16(af[ks], vf, oacc[db], 0, 0, 0);
      }
    __builtin_amdgcn_s_setprio(0);

    __syncthreads();   // tile t+1 staged (vmcnt drained) + all waves done with buf
    bufi ^= 1;
  }

  // epilogue: route 1/l to O-domain rows, store fp32 merge-heads layout
  float invl = 1.0f / lrun;   // for q = l31 (softmax domain)
#pragma unroll
  for (int reg = 0; reg < 16; ++reg) {
    int q_local = (reg & 3) + 8 * (reg >> 2) + 4 * hi;
    float inv_r = __shfl(invl, q_local);
    int q = qbase + q_local;
    out[((size_t)b * NS + q) * NHID + h * 64 + l31]      = oacc[0][reg] * inv_r;
    out[((size_t)b * NS + q) * NHID + h * 64 + 32 + l31] = oacc[1][reg] * inv_r;
  }
#undef STAGE
}

extern "C" void kernel_launch(void* const* d_in, const int* in_sizes, int n_in,
                              void* d_out, int out_size, void* d_ws, size_t ws_size,
                              hipStream_t stream) {
  const float* X    = (const float*)d_in[0];
  const float* mask = (const float*)d_in[1];
  const float* Wq   = (const float*)d_in[2];
  const float* bq   = (const float*)d_in[3];
  const float* Wk   = (const float*)d_in[4];
  const float* bk   = (const float*)d_in[5];
  const float* Wv   = (const float*)d_in[6];
  const float* bv   = (const float*)d_in[7];
  float* out = (float*)d_out;

  unsigned short* xb = (unsigned short*)d_out;            // scratch, overwritten by attn out
  unsigned short* wb = xb + (size_t)NB * NS * NHID;
  unsigned short* qw = (unsigned short*)d_ws;
  unsigned short* kw = qw + (size_t)NBH * NS * NHD;
  unsigned short* vw = kw + (size_t)NBH * NS * NHD;

  cvt_kernel<<<7872, 256, 0, stream>>>(X, Wq, Wk, Wv, xb, wb);
  qkv_gemm<<<dim3(64, 18), 256, 0, stream>>>(xb, wb, bq, bk, bv, qw, kw, vw);
  attn_kernel<<<768, 256, 0, stream>>>(qw, kw, vw, mask, out);
}